// Round 1
// baseline (1811.029 us; speedup 1.0000x reference)
//
#include <hip/hip_runtime.h>

#define B_ 8
#define CIN_ 4
#define H_ 512
#define W_ 512
#define HID_ 32
#define NCLS_ 19
#define HO_ 256
#define WO_ 256
#define UP_ 512
#define NPLANE (B_*NCLS_)          // 152
#define PLANE_ELEMS (UP_*UP_)      // 262144
#define KMED1 131071u
#define KMED2 131072u

// ---------- helpers ----------

__device__ __forceinline__ unsigned f2key(float f) {
  unsigned u = __float_as_uint(f);
  return (u & 0x80000000u) ? ~u : (u | 0x80000000u);
}
__device__ __forceinline__ float key2f(unsigned k) {
  unsigned u = (k & 0x80000000u) ? (k & 0x7FFFFFFFu) : ~k;
  return __uint_as_float(u);
}

// Bilinear upsample value, arithmetic pinned via fmaf so every kernel that
// computes it gets bit-identical results (median recompute MUST match the
// array written by the upsample kernel).
__device__ __forceinline__ float up_val(const float* __restrict__ p, int oy, int ox) {
  const float s = (float)(255.0 / 511.0);   // matches f32(255/511) in the reference
  float posy = (float)oy * s;
  int ly = (int)posy; if (ly > 254) ly = 254;
  float fy = posy - (float)ly;
  float posx = (float)ox * s;
  int lx = (int)posx; if (lx > 254) lx = 254;
  float fx = posx - (float)lx;
  const float* q = p + ly * WO_ + lx;
  float a = q[0], b = q[1], c = q[WO_], d = q[WO_ + 1];
  float r0 = fmaf(fx, b - a, a);
  float r1 = fmaf(fx, d - c, c);
  return fmaf(fy, r1 - r0, r0);
}

// ---------- conv1: (8,4,512,512) -> relu -> (8,32,256,256), stride 2, pad 1 ----------
// block 256 thr: t=tid&63 -> 4-wide output strip, r=tid>>6 -> row in 4-row tile
__global__ __launch_bounds__(256) void conv1_kernel(
    const float* __restrict__ x, const float* __restrict__ w1,
    const float* __restrict__ b1, float* __restrict__ h) {
  int t = threadIdx.x & 63;
  int r = threadIdx.x >> 6;
  int oh = blockIdx.x * 4 + r;     // 0..255
  int oc = blockIdx.y;             // 0..31
  int b  = blockIdx.z;             // 0..7
  int ow0 = t * 4;
  const float* wp = w1 + oc * (CIN_ * 9);
  float bias = b1[oc];
  float a0 = bias, a1 = bias, a2 = bias, a3 = bias;
  #pragma unroll
  for (int ci = 0; ci < CIN_; ++ci) {
    const float* xp = x + ((size_t)(b * CIN_ + ci)) * H_ * W_;
    #pragma unroll
    for (int kh = 0; kh < 3; ++kh) {
      int ih = 2 * oh + kh - 1;
      if ((unsigned)ih >= (unsigned)H_) continue;
      const float* row = xp + ih * W_;
      int c0i = 2 * ow0;           // cols needed: c0i-1 .. c0i+7
      float4 A = *reinterpret_cast<const float4*>(row + c0i);
      float4 Bv = *reinterpret_cast<const float4*>(row + c0i + 4);
      float lm = (c0i > 0) ? row[c0i - 1] : 0.f;
      float w0 = wp[ci * 9 + kh * 3 + 0];
      float w1v = wp[ci * 9 + kh * 3 + 1];
      float w2v = wp[ci * 9 + kh * 3 + 2];
      a0 += w0 * lm   + w1v * A.x + w2v * A.y;
      a1 += w0 * A.y  + w1v * A.z + w2v * A.w;
      a2 += w0 * A.w  + w1v * Bv.x + w2v * Bv.y;
      a3 += w0 * Bv.y + w1v * Bv.z + w2v * Bv.w;
    }
  }
  float4 o;
  o.x = fmaxf(a0, 0.f); o.y = fmaxf(a1, 0.f);
  o.z = fmaxf(a2, 0.f); o.w = fmaxf(a3, 0.f);
  *reinterpret_cast<float4*>(h + (((size_t)(b * HID_ + oc) * HO_ + oh) * WO_ + ow0)) = o;
}

// ---------- conv2: (8,32,256,256) -> (8,19,256,256), stride 1, pad 1 ----------
__global__ __launch_bounds__(256) void conv2_kernel(
    const float* __restrict__ h, const float* __restrict__ w2,
    const float* __restrict__ b2, float* __restrict__ c0) {
  int t = threadIdx.x & 63;
  int r = threadIdx.x >> 6;
  int oh = blockIdx.x * 4 + r;     // 0..255
  int oc = blockIdx.y;             // 0..18
  int b  = blockIdx.z;             // 0..7
  int ow0 = t * 4;
  const float* wp = w2 + oc * (HID_ * 9);
  float bias = b2[oc];
  float a0 = bias, a1 = bias, a2 = bias, a3 = bias;
  for (int ci = 0; ci < HID_; ++ci) {
    const float* hp = h + ((size_t)(b * HID_ + ci)) * HO_ * WO_;
    #pragma unroll
    for (int kh = 0; kh < 3; ++kh) {
      int ih = oh + kh - 1;
      if ((unsigned)ih >= (unsigned)HO_) continue;
      const float* row = hp + ih * WO_;
      float4 M = *reinterpret_cast<const float4*>(row + ow0);
      float lm = (ow0 > 0) ? row[ow0 - 1] : 0.f;
      float rp = (ow0 + 4 < WO_) ? row[ow0 + 4] : 0.f;
      float w0 = wp[ci * 9 + kh * 3 + 0];
      float w1v = wp[ci * 9 + kh * 3 + 1];
      float w2v = wp[ci * 9 + kh * 3 + 2];
      a0 += w0 * lm  + w1v * M.x + w2v * M.y;
      a1 += w0 * M.x + w1v * M.y + w2v * M.z;
      a2 += w0 * M.y + w1v * M.z + w2v * M.w;
      a3 += w0 * M.z + w1v * M.w + w2v * rp;
    }
  }
  float4 o; o.x = a0; o.y = a1; o.z = a2; o.w = a3;
  *reinterpret_cast<float4*>(c0 + (((size_t)(b * NCLS_ + oc) * HO_ + oh) * WO_ + ow0)) = o;
}

// ---------- upsample: (152,256,256) -> (152,512,512) written to d_out ----------
__global__ __launch_bounds__(256) void upsample_kernel(
    const float* __restrict__ c0, float* __restrict__ out) {
  int oy = blockIdx.x;             // 0..511
  int plane = blockIdx.y;          // 0..151
  const float* p = c0 + (size_t)plane * HO_ * WO_;
  float* orow = out + ((size_t)plane * UP_ + oy) * UP_;
  #pragma unroll
  for (int i = 0; i < 2; ++i) {
    int ox = threadIdx.x + i * 256;
    orow[ox] = up_val(p, oy, ox);
  }
}

// ---------- median: exact per-plane median of the 512x512 upsampled plane ----------
// One 1024-thread block per plane. Radix-select on sortable-uint keys,
// 3 passes (bits 31:21, 20:10, 9:0), values recomputed from c0 (L2-resident).
__global__ __launch_bounds__(1024) void median_kernel(
    const float* __restrict__ c0, float* __restrict__ med_out) {
  __shared__ unsigned hist[4 * 2049];   // 4 wave-privatized copies, +1 pad per copy
  __shared__ unsigned scanbuf[2048];
  __shared__ unsigned tmpbuf[2048];
  __shared__ unsigned sel[3];
  int tid = threadIdx.x;
  int plane = blockIdx.x;
  const float* p = c0 + (size_t)plane * HO_ * WO_;
  int copy = (tid >> 6) & 3;

  unsigned k = KMED1, gb = 0u, pmask = 0u, pval = 0u;
  const int shifts[3] = {21, 10, 0};
  const unsigned bmask[3] = {0x7FFu, 0x7FFu, 0x3FFu};

  for (int pass = 0; pass < 3; ++pass) {
    for (int i = tid; i < 4 * 2049; i += 1024) hist[i] = 0u;
    __syncthreads();
    for (int idx = tid; idx < PLANE_ELEMS; idx += 1024) {
      float v = up_val(p, idx >> 9, idx & (UP_ - 1));
      unsigned key = f2key(v);
      if ((key & pmask) == pval) {
        unsigned bin = (key >> shifts[pass]) & bmask[pass];
        atomicAdd(&hist[copy * 2049 + bin], 1u);
      }
    }
    __syncthreads();
    for (int i = tid; i < 2048; i += 1024)
      scanbuf[i] = hist[i] + hist[2049 + i] + hist[4098 + i] + hist[6147 + i];
    __syncthreads();
    // inclusive scan over 2048 bins (Hillis-Steele)
    for (int off = 1; off < 2048; off <<= 1) {
      for (int i = tid; i < 2048; i += 1024) tmpbuf[i] = (i >= off) ? scanbuf[i - off] : 0u;
      __syncthreads();
      for (int i = tid; i < 2048; i += 1024) scanbuf[i] += tmpbuf[i];
      __syncthreads();
    }
    for (int i = tid; i < 2048; i += 1024) {
      unsigned below = i ? scanbuf[i - 1] : 0u;
      if (below <= k && k < scanbuf[i]) {
        sel[0] = (unsigned)i; sel[1] = below; sel[2] = scanbuf[i] - below;
      }
    }
    __syncthreads();
    unsigned bin = sel[0], below = sel[1];
    k -= below; gb += below;
    pval |= bin << shifts[pass];
    pmask |= bmask[pass] << shifts[pass];
    __syncthreads();
  }

  unsigned v1key = pval;
  unsigned ceq = sel[2];              // global count of keys == v1key
  float v1 = key2f(v1key);
  float v2 = v1;
  if (KMED2 >= gb + ceq) {            // 131072nd order stat is the next larger key
    unsigned lmin = 0xFFFFFFFFu;
    for (int idx = tid; idx < PLANE_ELEMS; idx += 1024) {
      float v = up_val(p, idx >> 9, idx & (UP_ - 1));
      unsigned key = f2key(v);
      if (key > v1key && key < lmin) lmin = key;
    }
    scanbuf[tid] = lmin;
    __syncthreads();
    for (int s = 512; s > 0; s >>= 1) {
      if (tid < s) { unsigned o = scanbuf[tid + s]; if (o < scanbuf[tid]) scanbuf[tid] = o; }
      __syncthreads();
    }
    v2 = key2f(scanbuf[0]);
  }
  if (tid == 0) med_out[plane] = 0.5f * (v1 + v2);
}

// ---------- peak pass: 3x3 local max, compare to median, masked sum/count ----------
__global__ __launch_bounds__(256) void peak_kernel(
    const float* __restrict__ cm, const float* __restrict__ med_arr,
    float* __restrict__ sums, float* __restrict__ cnts) {
  int y = blockIdx.x;
  int plane = blockIdx.y;
  int tid = threadIdx.x;
  const float* p = cm + (size_t)plane * PLANE_ELEMS;
  float med = med_arr[plane];
  float lsum = 0.f; int lcnt = 0;
  #pragma unroll
  for (int i = 0; i < 2; ++i) {
    int x = tid + i * 256;
    float v = p[y * UP_ + x];
    float m = v;
    #pragma unroll
    for (int dy = -1; dy <= 1; ++dy) {
      int yy = y + dy;
      if ((unsigned)yy >= (unsigned)UP_) continue;
      const float* row = p + yy * UP_;
      #pragma unroll
      for (int dx = -1; dx <= 1; ++dx) {
        int xx = x + dx;
        if ((unsigned)xx >= (unsigned)UP_) continue;
        m = fmaxf(m, row[xx]);
      }
    }
    if (v == m && v >= med) { lsum += v; lcnt += 1; }
  }
  __shared__ float ss[256];
  __shared__ int sc[256];
  ss[tid] = lsum; sc[tid] = lcnt;
  __syncthreads();
  for (int s = 128; s > 0; s >>= 1) {
    if (tid < s) { ss[tid] += ss[tid + s]; sc[tid] += sc[tid + s]; }
    __syncthreads();
  }
  if (tid == 0) {
    atomicAdd(&sums[plane], ss[0]);
    atomicAdd(&cnts[plane], (float)sc[0]);
  }
}

__global__ void logits_kernel(const float* __restrict__ sums,
                              const float* __restrict__ cnts,
                              float* __restrict__ out) {
  int i = threadIdx.x;
  if (i < NPLANE) out[i] = sums[i] / cnts[i];
}

// ---------- launch ----------
extern "C" void kernel_launch(void* const* d_in, const int* in_sizes, int n_in,
                              void* d_out, int out_size, void* d_ws, size_t ws_size,
                              hipStream_t stream) {
  const float* x  = (const float*)d_in[0];
  const float* w1 = (const float*)d_in[1];
  const float* b1 = (const float*)d_in[2];
  const float* w2 = (const float*)d_in[3];
  const float* b2 = (const float*)d_in[4];
  float* out = (float*)d_out;

  float* ws = (float*)d_ws;
  float* c0   = ws;                          // 8*19*256*256 = 9,961,472 floats
  float* med  = ws + 9961472;                // 152
  float* sums = ws + 9961624;                // 152
  float* cnts = ws + 9961776;                // 152
  float* h = out;                            // conv1 output scratch (16.7M floats),
                                             // overwritten later by upsample

  hipMemsetAsync(sums, 0, 2 * NPLANE * sizeof(float), stream);

  conv1_kernel<<<dim3(64, 32, 8), 256, 0, stream>>>(x, w1, b1, h);
  conv2_kernel<<<dim3(64, 19, 8), 256, 0, stream>>>(h, w2, b2, c0);
  upsample_kernel<<<dim3(512, NPLANE), 256, 0, stream>>>(c0, out);
  median_kernel<<<dim3(NPLANE), 1024, 0, stream>>>(c0, med);
  peak_kernel<<<dim3(512, NPLANE), 256, 0, stream>>>(out, med, sums, cnts);
  logits_kernel<<<dim3(1), 192, 0, stream>>>(sums, cnts, out + (out_size - NPLANE));
}

// Round 2
// 1682.130 us; speedup vs baseline: 1.0766x; 1.0766x over previous
//
#include <hip/hip_runtime.h>

#define B_ 8
#define CIN_ 4
#define H_ 512
#define W_ 512
#define HID_ 32
#define NCLS_ 19
#define HO_ 256
#define WO_ 256
#define UP_ 512
#define NPLANE (B_*NCLS_)          // 152
#define PLANE_ELEMS (UP_*UP_)      // 262144
#define KMED1 131071u

// ---------- helpers ----------

__device__ __forceinline__ unsigned f2key(float f) {
  unsigned u = __float_as_uint(f);
  return (u & 0x80000000u) ? ~u : (u | 0x80000000u);
}
__device__ __forceinline__ float key2f(unsigned k) {
  unsigned u = (k & 0x80000000u) ? (k & 0x7FFFFFFFu) : ~k;
  return __uint_as_float(u);
}
__device__ __forceinline__ float ninf() { return __uint_as_float(0xFF800000u); }

// Bilinear upsample value (fmaf-pinned so all kernels agree bit-exactly).
__device__ __forceinline__ float up_val(const float* __restrict__ p, int oy, int ox) {
  const float s = (float)(255.0 / 511.0);
  float posy = (float)oy * s;
  int ly = (int)posy; if (ly > 254) ly = 254;
  float fy = posy - (float)ly;
  float posx = (float)ox * s;
  int lx = (int)posx; if (lx > 254) lx = 254;
  float fx = posx - (float)lx;
  const float* q = p + ly * WO_ + lx;
  float a = q[0], b = q[1], c = q[WO_], d = q[WO_ + 1];
  float r0 = fmaf(fx, b - a, a);
  float r1 = fmaf(fx, d - c, c);
  return fmaf(fy, r1 - r0, r0);
}

// ---------- conv1: (8,4,512,512) -> relu -> (8,32,256,256), stride 2, pad 1 ----------
__global__ __launch_bounds__(256) void conv1_kernel(
    const float* __restrict__ x, const float* __restrict__ w1,
    const float* __restrict__ b1, float* __restrict__ h) {
  int t = threadIdx.x & 63;
  int r = threadIdx.x >> 6;
  int oh = blockIdx.x * 4 + r;
  int oc = blockIdx.y;
  int b  = blockIdx.z;
  int ow0 = t * 4;
  const float* wp = w1 + oc * (CIN_ * 9);
  float bias = b1[oc];
  float a0 = bias, a1 = bias, a2 = bias, a3 = bias;
  #pragma unroll
  for (int ci = 0; ci < CIN_; ++ci) {
    const float* xp = x + ((size_t)(b * CIN_ + ci)) * H_ * W_;
    #pragma unroll
    for (int kh = 0; kh < 3; ++kh) {
      int ih = 2 * oh + kh - 1;
      if ((unsigned)ih >= (unsigned)H_) continue;
      const float* row = xp + ih * W_;
      int c0i = 2 * ow0;
      float4 A = *reinterpret_cast<const float4*>(row + c0i);
      float4 Bv = *reinterpret_cast<const float4*>(row + c0i + 4);
      float lm = (c0i > 0) ? row[c0i - 1] : 0.f;
      float w0 = wp[ci * 9 + kh * 3 + 0];
      float w1v = wp[ci * 9 + kh * 3 + 1];
      float w2v = wp[ci * 9 + kh * 3 + 2];
      a0 += w0 * lm   + w1v * A.x + w2v * A.y;
      a1 += w0 * A.y  + w1v * A.z + w2v * A.w;
      a2 += w0 * A.w  + w1v * Bv.x + w2v * Bv.y;
      a3 += w0 * Bv.y + w1v * Bv.z + w2v * Bv.w;
    }
  }
  float4 o;
  o.x = fmaxf(a0, 0.f); o.y = fmaxf(a1, 0.f);
  o.z = fmaxf(a2, 0.f); o.w = fmaxf(a3, 0.f);
  *reinterpret_cast<float4*>(h + (((size_t)(b * HID_ + oc) * HO_ + oh) * WO_ + ow0)) = o;
}

// ---------- conv2: (8,32,256,256) -> (8,19,256,256), stride 1, pad 1 ----------
__global__ __launch_bounds__(256) void conv2_kernel(
    const float* __restrict__ h, const float* __restrict__ w2,
    const float* __restrict__ b2, float* __restrict__ c0) {
  int t = threadIdx.x & 63;
  int r = threadIdx.x >> 6;
  int oh = blockIdx.x * 4 + r;
  int oc = blockIdx.y;
  int b  = blockIdx.z;
  int ow0 = t * 4;
  const float* wp = w2 + oc * (HID_ * 9);
  float bias = b2[oc];
  float a0 = bias, a1 = bias, a2 = bias, a3 = bias;
  for (int ci = 0; ci < HID_; ++ci) {
    const float* hp = h + ((size_t)(b * HID_ + ci)) * HO_ * WO_;
    #pragma unroll
    for (int kh = 0; kh < 3; ++kh) {
      int ih = oh + kh - 1;
      if ((unsigned)ih >= (unsigned)HO_) continue;
      const float* row = hp + ih * WO_;
      float4 M = *reinterpret_cast<const float4*>(row + ow0);
      float lm = (ow0 > 0) ? row[ow0 - 1] : 0.f;
      float rp = (ow0 + 4 < WO_) ? row[ow0 + 4] : 0.f;
      float w0 = wp[ci * 9 + kh * 3 + 0];
      float w1v = wp[ci * 9 + kh * 3 + 1];
      float w2v = wp[ci * 9 + kh * 3 + 2];
      a0 += w0 * lm  + w1v * M.x + w2v * M.y;
      a1 += w0 * M.x + w1v * M.y + w2v * M.z;
      a2 += w0 * M.y + w1v * M.z + w2v * M.w;
      a3 += w0 * M.z + w1v * M.w + w2v * rp;
    }
  }
  float4 o; o.x = a0; o.y = a1; o.z = a2; o.w = a3;
  *reinterpret_cast<float4*>(c0 + (((size_t)(b * NCLS_ + oc) * HO_ + oh) * WO_ + ow0)) = o;
}

// ---------- upsample: (152,256,256) -> (152,512,512) written to d_out ----------
__global__ __launch_bounds__(256) void upsample_kernel(
    const float* __restrict__ c0, float* __restrict__ out) {
  int oy = blockIdx.x;
  int plane = blockIdx.y;
  const float* p = c0 + (size_t)plane * HO_ * WO_;
  float* orow = out + ((size_t)plane * UP_ + oy) * UP_;
  #pragma unroll
  for (int i = 0; i < 2; ++i) {
    int ox = threadIdx.x + i * 256;
    orow[ox] = up_val(p, oy, ox);
  }
}

// ---------- median machinery: chip-wide 3-pass radix select over d_out ----------

__global__ void init_kernel(unsigned* kArr, unsigned* pvalArr, unsigned* gbArr,
                            unsigned* flagArr) {
  int i = threadIdx.x;
  if (i < NPLANE) { kArr[i] = KMED1; pvalArr[i] = 0u; gbArr[i] = 0u; flagArr[i] = 0u; }
}

// wave-aggregated LDS histogram add: cost ~ #distinct bins in wave (bounds
// same-address LDS-atomic serialization when values cluster in few bins)
__device__ __forceinline__ void agg_add(unsigned* lh, unsigned bin, bool want) {
  int lane = threadIdx.x & 63;
  bool pend = want;
  while (true) {
    unsigned long long act = __ballot(pend);
    if (act == 0ull) break;
    int src = __ffsll((unsigned long long)act) - 1;
    unsigned b = __shfl(bin, src, 64);
    bool same = pend && (bin == b);
    unsigned long long sm = __ballot(same);
    if (lane == src) atomicAdd(&lh[b], (unsigned)__popcll(sm));
    if (same) pend = false;
  }
}

__global__ __launch_bounds__(256) void hist_kernel(
    const float* __restrict__ up, const unsigned* __restrict__ pvalArr,
    unsigned* __restrict__ ghist, int shift, unsigned bmask, unsigned fmask) {
  __shared__ unsigned lh[2048];
  int tid = threadIdx.x;
  int chunk = blockIdx.x;   // 16 chunks
  int plane = blockIdx.y;   // 152 planes
  for (int i = tid; i < 2048; i += 256) lh[i] = 0u;
  __syncthreads();
  unsigned fval = pvalArr[plane] & fmask;
  const float4* base = reinterpret_cast<const float4*>(up + (size_t)plane * PLANE_ELEMS)
                       + (size_t)chunk * 4096;
  for (int it = 0; it < 16; ++it) {
    float4 v = base[it * 256 + tid];
    unsigned k0 = f2key(v.x), k1 = f2key(v.y), k2 = f2key(v.z), k3 = f2key(v.w);
    agg_add(lh, (k0 >> shift) & bmask, (k0 & fmask) == fval);
    agg_add(lh, (k1 >> shift) & bmask, (k1 & fmask) == fval);
    agg_add(lh, (k2 >> shift) & bmask, (k2 & fmask) == fval);
    agg_add(lh, (k3 >> shift) & bmask, (k3 & fmask) == fval);
  }
  __syncthreads();
  for (int i = tid; i < 2048; i += 256) {
    unsigned c = lh[i];
    if (c) atomicAdd(&ghist[(size_t)plane * 2048 + i], c);
  }
}

__global__ __launch_bounds__(256) void select_kernel(
    unsigned* __restrict__ ghist, unsigned* kArr, unsigned* pvalArr, unsigned* gbArr,
    unsigned* v1Arr, unsigned* v2Arr, unsigned* flagArr,
    int shift, unsigned bmask, int nbins, int last) {
  __shared__ unsigned ssum[256], stmp[256];
  __shared__ unsigned sBin, sBelow, sCand[256];
  int tid = threadIdx.x;
  int plane = blockIdx.x;
  unsigned* hp = ghist + (size_t)plane * 2048;
  unsigned k = kArr[plane];
  unsigned lv[8];
  int b0 = tid * 8;
  unsigned lsum = 0;
  #pragma unroll
  for (int j = 0; j < 8; ++j) {
    unsigned c = (b0 + j < nbins) ? hp[b0 + j] : 0u;
    lv[j] = c; lsum += c;
  }
  ssum[tid] = lsum;
  __syncthreads();
  for (int off = 1; off < 256; off <<= 1) {
    stmp[tid] = (tid >= off) ? ssum[tid - off] : 0u; __syncthreads();
    ssum[tid] += stmp[tid]; __syncthreads();
  }
  unsigned incl = ssum[tid], excl = incl - lsum;
  if (excl <= k && k < incl) {
    unsigned kk = k - excl, below = excl;
    #pragma unroll
    for (int j = 0; j < 8; ++j) {
      if (kk < lv[j]) { sBin = (unsigned)(b0 + j); sBelow = below; break; }
      kk -= lv[j]; below += lv[j];
    }
  }
  __syncthreads();
  unsigned bin = sBin, below = sBelow;
  unsigned pvalNew = pvalArr[plane] | (bin << shift);
  unsigned gbNew = gbArr[plane] + below;
  if (!last) {
    for (int i = tid; i < 2048; i += 256) hp[i] = 0u;   // ready for next pass
    if (tid == 0) { kArr[plane] = k - below; pvalArr[plane] = pvalNew; gbArr[plane] = gbNew; }
  } else {
    // pass-3 bins are exact keys within the 22-bit prefix
    unsigned cand = 0xFFFFFFFFu;
    #pragma unroll
    for (int j = 0; j < 8; ++j) {
      int g = b0 + j;
      if (g > (int)bin && g < nbins && lv[j] > 0u && (unsigned)g < cand) cand = (unsigned)g;
    }
    sCand[tid] = cand;
    __syncthreads();
    for (int s = 128; s > 0; s >>= 1) {
      if (tid < s) { unsigned o = sCand[tid + s]; if (o < sCand[tid]) sCand[tid] = o; }
      __syncthreads();
    }
    if (tid == 0) {
      unsigned ceq = hp[bin];      // count of keys == v1key
      v1Arr[plane] = pvalNew;
      if (131072u < gbNew + ceq) {          // rank-131072 inside the equal run
        v2Arr[plane] = pvalNew; flagArr[plane] = 0u;
      } else if (sCand[0] != 0xFFFFFFFFu) { // next key shares the 22-bit prefix
        v2Arr[plane] = (pvalNew & ~(bmask << shift)) | (sCand[0] << shift);
        flagArr[plane] = 0u;
      } else {                              // rare: need global min key > v1key
        v2Arr[plane] = 0xFFFFFFFFu; flagArr[plane] = 1u;
      }
    }
  }
}

__global__ __launch_bounds__(256) void minabove_kernel(
    const float* __restrict__ up, const unsigned* __restrict__ flagArr,
    const unsigned* __restrict__ v1Arr, unsigned* __restrict__ v2Arr) {
  int plane = blockIdx.y, chunk = blockIdx.x, tid = threadIdx.x;
  if (!flagArr[plane]) return;   // usually taken -> near-zero cost
  unsigned v1 = v1Arr[plane];
  const float4* base = reinterpret_cast<const float4*>(up + (size_t)plane * PLANE_ELEMS)
                       + (size_t)chunk * 4096;
  unsigned m = 0xFFFFFFFFu;
  for (int it = 0; it < 16; ++it) {
    float4 v = base[it * 256 + tid];
    unsigned k;
    k = f2key(v.x); if (k > v1 && k < m) m = k;
    k = f2key(v.y); if (k > v1 && k < m) m = k;
    k = f2key(v.z); if (k > v1 && k < m) m = k;
    k = f2key(v.w); if (k > v1 && k < m) m = k;
  }
  for (int off = 32; off > 0; off >>= 1) {
    unsigned o = __shfl_down(m, off, 64);
    if (o < m) m = o;
  }
  if ((tid & 63) == 0) atomicMin(&v2Arr[plane], m);
}

__global__ void finalize_kernel(const unsigned* __restrict__ v1Arr,
                                const unsigned* __restrict__ v2Arr,
                                float* __restrict__ med) {
  int i = threadIdx.x;
  if (i < NPLANE) med[i] = 0.5f * (key2f(v1Arr[i]) + key2f(v2Arr[i]));
}

// ---------- peak pass: rolling-register 3x3 local max + masked sum ----------
// thread: 4-wide column strip, walks 64 rows; each element loaded once (float4)
__device__ __forceinline__ void row_load(const float* __restrict__ p, int y, int x0,
                                         float4& v, float& l, float& r) {
  if ((unsigned)y >= (unsigned)UP_) {
    float ni = ninf();
    v.x = v.y = v.z = v.w = ni; l = ni; r = ni;
    return;
  }
  const float* row = p + y * UP_ + x0;
  v = *reinterpret_cast<const float4*>(row);
  l = (x0 > 0) ? row[-1] : ninf();
  r = (x0 < UP_ - 4) ? row[4] : ninf();
}
__device__ __forceinline__ float4 hmax4(const float4& v, float l, float r) {
  float4 h;
  h.x = fmaxf(fmaxf(l, v.x), v.y);
  h.y = fmaxf(fmaxf(v.x, v.y), v.z);
  h.z = fmaxf(fmaxf(v.y, v.z), v.w);
  h.w = fmaxf(fmaxf(v.z, v.w), r);
  return h;
}

__global__ __launch_bounds__(256) void peak2_kernel(
    const float* __restrict__ cm, const float* __restrict__ med_arr,
    float* __restrict__ sums, float* __restrict__ cnts) {
  int tid = threadIdx.x;
  int plane = blockIdx.x;                 // 152
  int strip = tid & 127;                  // 128 strips of 4 cols
  int ychunk = blockIdx.y * 2 + (tid >> 7); // 8 chunks of 64 rows
  int x0 = strip * 4;
  int ystart = ychunk * 64;
  const float* p = cm + (size_t)plane * PLANE_ELEMS;
  float med = med_arr[plane];

  float4 v, vn; float l, r;
  row_load(p, ystart - 1, x0, v, l, r);
  float4 hprev = hmax4(v, l, r);
  row_load(p, ystart, x0, v, l, r);
  float4 hcur = hmax4(v, l, r);
  float4 vcur = v;

  float lsum = 0.f; int lcnt = 0;
  for (int yi = 0; yi < 64; ++yi) {
    int y = ystart + yi;
    float ln, rn;
    row_load(p, y + 1, x0, vn, ln, rn);
    float4 hnext = hmax4(vn, ln, rn);
    float mx = fmaxf(fmaxf(hprev.x, hcur.x), hnext.x);
    float my = fmaxf(fmaxf(hprev.y, hcur.y), hnext.y);
    float mz = fmaxf(fmaxf(hprev.z, hcur.z), hnext.z);
    float mw = fmaxf(fmaxf(hprev.w, hcur.w), hnext.w);
    if (vcur.x == mx && vcur.x >= med) { lsum += vcur.x; ++lcnt; }
    if (vcur.y == my && vcur.y >= med) { lsum += vcur.y; ++lcnt; }
    if (vcur.z == mz && vcur.z >= med) { lsum += vcur.z; ++lcnt; }
    if (vcur.w == mw && vcur.w >= med) { lsum += vcur.w; ++lcnt; }
    hprev = hcur; hcur = hnext; vcur = vn;
  }

  __shared__ float ss[256];
  __shared__ int sc[256];
  ss[tid] = lsum; sc[tid] = lcnt;
  __syncthreads();
  for (int s = 128; s > 0; s >>= 1) {
    if (tid < s) { ss[tid] += ss[tid + s]; sc[tid] += sc[tid + s]; }
    __syncthreads();
  }
  if (tid == 0) {
    atomicAdd(&sums[plane], ss[0]);
    atomicAdd(&cnts[plane], (float)sc[0]);
  }
}

__global__ void logits_kernel(const float* __restrict__ sums,
                              const float* __restrict__ cnts,
                              float* __restrict__ out) {
  int i = threadIdx.x;
  if (i < NPLANE) out[i] = sums[i] / cnts[i];
}

// ---------- launch ----------
extern "C" void kernel_launch(void* const* d_in, const int* in_sizes, int n_in,
                              void* d_out, int out_size, void* d_ws, size_t ws_size,
                              hipStream_t stream) {
  const float* x  = (const float*)d_in[0];
  const float* w1 = (const float*)d_in[1];
  const float* b1 = (const float*)d_in[2];
  const float* w2 = (const float*)d_in[3];
  const float* b2 = (const float*)d_in[4];
  float* out = (float*)d_out;

  float* ws = (float*)d_ws;
  float* c0 = ws;                                      // 9,961,472 floats
  unsigned* hist    = (unsigned*)(ws + 9961472);       // 152*2048 = 311,296
  unsigned* kArr    = hist + 311296;
  unsigned* pvalArr = kArr + NPLANE;
  unsigned* gbArr   = pvalArr + NPLANE;
  unsigned* v1Arr   = gbArr + NPLANE;
  unsigned* v2Arr   = v1Arr + NPLANE;
  unsigned* flagArr = v2Arr + NPLANE;
  float* med  = (float*)(flagArr + NPLANE);
  float* sums = med + NPLANE;
  float* cnts = sums + NPLANE;
  float* h = out;   // conv1 scratch; fully overwritten by upsample

  init_kernel<<<1, 256, 0, stream>>>(kArr, pvalArr, gbArr, flagArr);
  hipMemsetAsync(hist, 0, (size_t)NPLANE * 2048 * sizeof(unsigned), stream);
  hipMemsetAsync(sums, 0, 2 * NPLANE * sizeof(float), stream);

  conv1_kernel<<<dim3(64, 32, 8), 256, 0, stream>>>(x, w1, b1, h);
  conv2_kernel<<<dim3(64, 19, 8), 256, 0, stream>>>(h, w2, b2, c0);
  upsample_kernel<<<dim3(512, NPLANE), 256, 0, stream>>>(c0, out);

  // radix select: bits 31:21, 20:10, 9:0
  hist_kernel<<<dim3(16, NPLANE), 256, 0, stream>>>(out, pvalArr, hist, 21, 0x7FFu, 0x00000000u);
  select_kernel<<<dim3(NPLANE), 256, 0, stream>>>(hist, kArr, pvalArr, gbArr,
      v1Arr, v2Arr, flagArr, 21, 0x7FFu, 2048, 0);
  hist_kernel<<<dim3(16, NPLANE), 256, 0, stream>>>(out, pvalArr, hist, 10, 0x7FFu, 0xFFE00000u);
  select_kernel<<<dim3(NPLANE), 256, 0, stream>>>(hist, kArr, pvalArr, gbArr,
      v1Arr, v2Arr, flagArr, 10, 0x7FFu, 2048, 0);
  hist_kernel<<<dim3(16, NPLANE), 256, 0, stream>>>(out, pvalArr, hist, 0, 0x3FFu, 0xFFFFFC00u);
  select_kernel<<<dim3(NPLANE), 256, 0, stream>>>(hist, kArr, pvalArr, gbArr,
      v1Arr, v2Arr, flagArr, 0, 0x3FFu, 1024, 1);
  minabove_kernel<<<dim3(16, NPLANE), 256, 0, stream>>>(out, flagArr, v1Arr, v2Arr);
  finalize_kernel<<<1, 256, 0, stream>>>(v1Arr, v2Arr, med);

  peak2_kernel<<<dim3(NPLANE, 4), 256, 0, stream>>>(out, med, sums, cnts);
  logits_kernel<<<1, 192, 0, stream>>>(sums, cnts, out + (out_size - NPLANE));
}

// Round 3
// 1160.876 us; speedup vs baseline: 1.5601x; 1.4490x over previous
//
#include <hip/hip_runtime.h>

#define B_ 8
#define CIN_ 4
#define H_ 512
#define W_ 512
#define HID_ 32
#define NCLS_ 19
#define HO_ 256
#define WO_ 256
#define UP_ 512
#define NPLANE (B_*NCLS_)          // 152
#define PLANE_ELEMS (UP_*UP_)      // 262144
#define KMED1 131071u

// ---------- helpers ----------

__device__ __forceinline__ unsigned f2key(float f) {
  unsigned u = __float_as_uint(f);
  return (u & 0x80000000u) ? ~u : (u | 0x80000000u);
}
__device__ __forceinline__ float key2f(unsigned k) {
  unsigned u = (k & 0x80000000u) ? (k & 0x7FFFFFFFu) : ~k;
  return __uint_as_float(u);
}
__device__ __forceinline__ float ninf() { return __uint_as_float(0xFF800000u); }

// Bilinear upsample value (fmaf-pinned so all kernels agree bit-exactly).
__device__ __forceinline__ float up_val(const float* __restrict__ p, int oy, int ox) {
  const float s = (float)(255.0 / 511.0);
  float posy = (float)oy * s;
  int ly = (int)posy; if (ly > 254) ly = 254;
  float fy = posy - (float)ly;
  float posx = (float)ox * s;
  int lx = (int)posx; if (lx > 254) lx = 254;
  float fx = posx - (float)lx;
  const float* q = p + ly * WO_ + lx;
  float a = q[0], b = q[1], c = q[WO_], d = q[WO_ + 1];
  float r0 = fmaf(fx, b - a, a);
  float r1 = fmaf(fx, d - c, c);
  return fmaf(fy, r1 - r0, r0);
}

// ---------- conv1: (8,4,512,512) -> relu -> (8,32,256,256), stride 2, pad 1 ----------
__global__ __launch_bounds__(256) void conv1_kernel(
    const float* __restrict__ x, const float* __restrict__ w1,
    const float* __restrict__ b1, float* __restrict__ h) {
  int t = threadIdx.x & 63;
  int r = threadIdx.x >> 6;
  int oh = blockIdx.x * 4 + r;
  int oc = blockIdx.y;
  int b  = blockIdx.z;
  int ow0 = t * 4;
  const float* wp = w1 + oc * (CIN_ * 9);
  float bias = b1[oc];
  float a0 = bias, a1 = bias, a2 = bias, a3 = bias;
  #pragma unroll
  for (int ci = 0; ci < CIN_; ++ci) {
    const float* xp = x + ((size_t)(b * CIN_ + ci)) * H_ * W_;
    #pragma unroll
    for (int kh = 0; kh < 3; ++kh) {
      int ih = 2 * oh + kh - 1;
      if ((unsigned)ih >= (unsigned)H_) continue;
      const float* row = xp + ih * W_;
      int c0i = 2 * ow0;
      float4 A = *reinterpret_cast<const float4*>(row + c0i);
      float4 Bv = *reinterpret_cast<const float4*>(row + c0i + 4);
      float lm = (c0i > 0) ? row[c0i - 1] : 0.f;
      float w0 = wp[ci * 9 + kh * 3 + 0];
      float w1v = wp[ci * 9 + kh * 3 + 1];
      float w2v = wp[ci * 9 + kh * 3 + 2];
      a0 += w0 * lm   + w1v * A.x + w2v * A.y;
      a1 += w0 * A.y  + w1v * A.z + w2v * A.w;
      a2 += w0 * A.w  + w1v * Bv.x + w2v * Bv.y;
      a3 += w0 * Bv.y + w1v * Bv.z + w2v * Bv.w;
    }
  }
  float4 o;
  o.x = fmaxf(a0, 0.f); o.y = fmaxf(a1, 0.f);
  o.z = fmaxf(a2, 0.f); o.w = fmaxf(a3, 0.f);
  *reinterpret_cast<float4*>(h + (((size_t)(b * HID_ + oc) * HO_ + oh) * WO_ + ow0)) = o;
}

// ---------- conv2: (8,32,256,256) -> (8,19,256,256), stride 1, pad 1 ----------
__global__ __launch_bounds__(256) void conv2_kernel(
    const float* __restrict__ h, const float* __restrict__ w2,
    const float* __restrict__ b2, float* __restrict__ c0) {
  int t = threadIdx.x & 63;
  int r = threadIdx.x >> 6;
  int oh = blockIdx.x * 4 + r;
  int oc = blockIdx.y;
  int b  = blockIdx.z;
  int ow0 = t * 4;
  const float* wp = w2 + oc * (HID_ * 9);
  float bias = b2[oc];
  float a0 = bias, a1 = bias, a2 = bias, a3 = bias;
  for (int ci = 0; ci < HID_; ++ci) {
    const float* hp = h + ((size_t)(b * HID_ + ci)) * HO_ * WO_;
    #pragma unroll
    for (int kh = 0; kh < 3; ++kh) {
      int ih = oh + kh - 1;
      if ((unsigned)ih >= (unsigned)HO_) continue;
      const float* row = hp + ih * WO_;
      float4 M = *reinterpret_cast<const float4*>(row + ow0);
      float lm = (ow0 > 0) ? row[ow0 - 1] : 0.f;
      float rp = (ow0 + 4 < WO_) ? row[ow0 + 4] : 0.f;
      float w0 = wp[ci * 9 + kh * 3 + 0];
      float w1v = wp[ci * 9 + kh * 3 + 1];
      float w2v = wp[ci * 9 + kh * 3 + 2];
      a0 += w0 * lm  + w1v * M.x + w2v * M.y;
      a1 += w0 * M.x + w1v * M.y + w2v * M.z;
      a2 += w0 * M.y + w1v * M.z + w2v * M.w;
      a3 += w0 * M.z + w1v * M.w + w2v * rp;
    }
  }
  float4 o; o.x = a0; o.y = a1; o.z = a2; o.w = a3;
  *reinterpret_cast<float4*>(c0 + (((size_t)(b * NCLS_ + oc) * HO_ + oh) * WO_ + ow0)) = o;
}

// ---------- upsample: (152,256,256) -> (152,512,512), float4 stores ----------
__global__ __launch_bounds__(256) void upsample_kernel(
    const float* __restrict__ c0, float* __restrict__ out) {
  int tid = threadIdx.x;
  int oy = blockIdx.x * 2 + (tid >> 7);   // 2 rows per block
  int t = tid & 127;
  int plane = blockIdx.y;
  const float* p = c0 + (size_t)plane * HO_ * WO_;
  int ox0 = t * 4;
  float4 o;
  o.x = up_val(p, oy, ox0 + 0);
  o.y = up_val(p, oy, ox0 + 1);
  o.z = up_val(p, oy, ox0 + 2);
  o.w = up_val(p, oy, ox0 + 3);
  *reinterpret_cast<float4*>(out + ((size_t)plane * UP_ + oy) * UP_ + ox0) = o;
}

// ---------- median machinery: 3-pass radix select, recomputing from c0 ----------

__global__ void init_kernel(unsigned* kArr, unsigned* pvalArr, unsigned* gbArr,
                            unsigned* flagArr) {
  int i = threadIdx.x;
  if (i < NPLANE) { kArr[i] = KMED1; pvalArr[i] = 0u; gbArr[i] = 0u; flagArr[i] = 0u; }
}

// grid (8 row-chunks, 152 planes), block 256. Wave-privatized LDS histograms,
// plain atomicAdd (same-address cost = multiplicity, ~10x cheaper than the
// ballot-aggregation loop that was 600us in R2).
__global__ __launch_bounds__(256) void hist_pass_kernel(
    const float* __restrict__ c0, const unsigned* __restrict__ pvalArr,
    unsigned* __restrict__ ghist, int shift, unsigned bmask, unsigned fmask) {
  __shared__ unsigned lh[4 * 2048];
  int tid = threadIdx.x;
  int chunk = blockIdx.x;   // 8 chunks of 64 rows
  int plane = blockIdx.y;
  unsigned* mylh = lh + ((tid >> 6) << 11);
  for (int i = tid; i < 4 * 2048; i += 256) lh[i] = 0u;
  __syncthreads();
  unsigned fval = pvalArr[plane] & fmask;
  const float* p = c0 + (size_t)plane * HO_ * WO_;
  int base = chunk * 64 * UP_;
  for (int idx = tid; idx < 64 * UP_; idx += 256) {
    int g = base + idx;
    float v = up_val(p, g >> 9, g & (UP_ - 1));
    unsigned key = f2key(v);
    if ((key & fmask) == fval)
      atomicAdd(&mylh[(key >> shift) & bmask], 1u);
  }
  __syncthreads();
  for (int i = tid; i < 2048; i += 256) {
    unsigned c = lh[i] + lh[2048 + i] + lh[4096 + i] + lh[6144 + i];
    if (c) atomicAdd(&ghist[(size_t)plane * 2048 + i], c);
  }
}

__global__ __launch_bounds__(256) void select_kernel(
    unsigned* __restrict__ ghist, unsigned* kArr, unsigned* pvalArr, unsigned* gbArr,
    unsigned* v1Arr, unsigned* v2Arr, unsigned* flagArr,
    int shift, unsigned bmask, int nbins, int last) {
  __shared__ unsigned ssum[256], stmp[256];
  __shared__ unsigned sBin, sBelow, sCand[256];
  int tid = threadIdx.x;
  int plane = blockIdx.x;
  unsigned* hp = ghist + (size_t)plane * 2048;
  unsigned k = kArr[plane];
  unsigned lv[8];
  int b0 = tid * 8;
  unsigned lsum = 0;
  #pragma unroll
  for (int j = 0; j < 8; ++j) {
    unsigned c = (b0 + j < nbins) ? hp[b0 + j] : 0u;
    lv[j] = c; lsum += c;
  }
  ssum[tid] = lsum;
  __syncthreads();
  for (int off = 1; off < 256; off <<= 1) {
    stmp[tid] = (tid >= off) ? ssum[tid - off] : 0u; __syncthreads();
    ssum[tid] += stmp[tid]; __syncthreads();
  }
  unsigned incl = ssum[tid], excl = incl - lsum;
  if (excl <= k && k < incl) {
    unsigned kk = k - excl, below = excl;
    #pragma unroll
    for (int j = 0; j < 8; ++j) {
      if (kk < lv[j]) { sBin = (unsigned)(b0 + j); sBelow = below; break; }
      kk -= lv[j]; below += lv[j];
    }
  }
  __syncthreads();
  unsigned bin = sBin, below = sBelow;
  unsigned pvalNew = pvalArr[plane] | (bin << shift);
  unsigned gbNew = gbArr[plane] + below;
  if (!last) {
    for (int i = tid; i < 2048; i += 256) hp[i] = 0u;   // ready for next pass
    if (tid == 0) { kArr[plane] = k - below; pvalArr[plane] = pvalNew; gbArr[plane] = gbNew; }
  } else {
    // pass-3 bins are exact keys within the 22-bit prefix
    unsigned cand = 0xFFFFFFFFu;
    #pragma unroll
    for (int j = 0; j < 8; ++j) {
      int g = b0 + j;
      if (g > (int)bin && g < nbins && lv[j] > 0u && (unsigned)g < cand) cand = (unsigned)g;
    }
    sCand[tid] = cand;
    __syncthreads();
    for (int s = 128; s > 0; s >>= 1) {
      if (tid < s) { unsigned o = sCand[tid + s]; if (o < sCand[tid]) sCand[tid] = o; }
      __syncthreads();
    }
    if (tid == 0) {
      unsigned ceq = hp[bin];      // count of keys == v1key
      v1Arr[plane] = pvalNew;
      if (131072u < gbNew + ceq) {          // rank-131072 inside the equal run
        v2Arr[plane] = pvalNew; flagArr[plane] = 0u;
      } else if (sCand[0] != 0xFFFFFFFFu) { // next key shares the 22-bit prefix
        v2Arr[plane] = (pvalNew & ~(bmask << shift)) | (sCand[0] << shift);
        flagArr[plane] = 0u;
      } else {                              // rare: need global min key > v1key
        v2Arr[plane] = 0xFFFFFFFFu; flagArr[plane] = 1u;
      }
    }
  }
}

__global__ __launch_bounds__(256) void minabove_kernel(
    const float* __restrict__ up, const unsigned* __restrict__ flagArr,
    const unsigned* __restrict__ v1Arr, unsigned* __restrict__ v2Arr) {
  int plane = blockIdx.y, chunk = blockIdx.x, tid = threadIdx.x;
  if (!flagArr[plane]) return;   // usually taken -> near-zero cost
  unsigned v1 = v1Arr[plane];
  const float4* base = reinterpret_cast<const float4*>(up + (size_t)plane * PLANE_ELEMS)
                       + (size_t)chunk * 4096;
  unsigned m = 0xFFFFFFFFu;
  for (int it = 0; it < 16; ++it) {
    float4 v = base[it * 256 + tid];
    unsigned k;
    k = f2key(v.x); if (k > v1 && k < m) m = k;
    k = f2key(v.y); if (k > v1 && k < m) m = k;
    k = f2key(v.z); if (k > v1 && k < m) m = k;
    k = f2key(v.w); if (k > v1 && k < m) m = k;
  }
  for (int off = 32; off > 0; off >>= 1) {
    unsigned o = __shfl_down(m, off, 64);
    if (o < m) m = o;
  }
  if ((tid & 63) == 0) atomicMin(&v2Arr[plane], m);
}

__global__ void finalize_kernel(const unsigned* __restrict__ v1Arr,
                                const unsigned* __restrict__ v2Arr,
                                float* __restrict__ med) {
  int i = threadIdx.x;
  if (i < NPLANE) med[i] = 0.5f * (key2f(v1Arr[i]) + key2f(v2Arr[i]));
}

// ---------- peak pass: rolling-register 3x3 local max + masked sum ----------
__device__ __forceinline__ void row_load(const float* __restrict__ p, int y, int x0,
                                         float4& v, float& l, float& r) {
  if ((unsigned)y >= (unsigned)UP_) {
    float ni = ninf();
    v.x = v.y = v.z = v.w = ni; l = ni; r = ni;
    return;
  }
  const float* row = p + y * UP_ + x0;
  v = *reinterpret_cast<const float4*>(row);
  l = (x0 > 0) ? row[-1] : ninf();
  r = (x0 < UP_ - 4) ? row[4] : ninf();
}
__device__ __forceinline__ float4 hmax4(const float4& v, float l, float r) {
  float4 h;
  h.x = fmaxf(fmaxf(l, v.x), v.y);
  h.y = fmaxf(fmaxf(v.x, v.y), v.z);
  h.z = fmaxf(fmaxf(v.y, v.z), v.w);
  h.w = fmaxf(fmaxf(v.z, v.w), r);
  return h;
}

__global__ __launch_bounds__(256) void peak2_kernel(
    const float* __restrict__ cm, const float* __restrict__ med_arr,
    float* __restrict__ sums, float* __restrict__ cnts) {
  int tid = threadIdx.x;
  int plane = blockIdx.x;                   // 152
  int strip = tid & 127;                    // 128 strips of 4 cols
  int ychunk = blockIdx.y * 2 + (tid >> 7); // 8 chunks of 64 rows
  int x0 = strip * 4;
  int ystart = ychunk * 64;
  const float* p = cm + (size_t)plane * PLANE_ELEMS;
  float med = med_arr[plane];

  float4 v, vn; float l, r;
  row_load(p, ystart - 1, x0, v, l, r);
  float4 hprev = hmax4(v, l, r);
  row_load(p, ystart, x0, v, l, r);
  float4 hcur = hmax4(v, l, r);
  float4 vcur = v;

  float lsum = 0.f; int lcnt = 0;
  for (int yi = 0; yi < 64; ++yi) {
    int y = ystart + yi;
    float ln, rn;
    row_load(p, y + 1, x0, vn, ln, rn);
    float4 hnext = hmax4(vn, ln, rn);
    float mx = fmaxf(fmaxf(hprev.x, hcur.x), hnext.x);
    float my = fmaxf(fmaxf(hprev.y, hcur.y), hnext.y);
    float mz = fmaxf(fmaxf(hprev.z, hcur.z), hnext.z);
    float mw = fmaxf(fmaxf(hprev.w, hcur.w), hnext.w);
    if (vcur.x == mx && vcur.x >= med) { lsum += vcur.x; ++lcnt; }
    if (vcur.y == my && vcur.y >= med) { lsum += vcur.y; ++lcnt; }
    if (vcur.z == mz && vcur.z >= med) { lsum += vcur.z; ++lcnt; }
    if (vcur.w == mw && vcur.w >= med) { lsum += vcur.w; ++lcnt; }
    hprev = hcur; hcur = hnext; vcur = vn;
  }

  __shared__ float ss[256];
  __shared__ int sc[256];
  ss[tid] = lsum; sc[tid] = lcnt;
  __syncthreads();
  for (int s = 128; s > 0; s >>= 1) {
    if (tid < s) { ss[tid] += ss[tid + s]; sc[tid] += sc[tid + s]; }
    __syncthreads();
  }
  if (tid == 0) {
    atomicAdd(&sums[plane], ss[0]);
    atomicAdd(&cnts[plane], (float)sc[0]);
  }
}

__global__ void logits_kernel(const float* __restrict__ sums,
                              const float* __restrict__ cnts,
                              float* __restrict__ out) {
  int i = threadIdx.x;
  if (i < NPLANE) out[i] = sums[i] / cnts[i];
}

// ---------- launch ----------
extern "C" void kernel_launch(void* const* d_in, const int* in_sizes, int n_in,
                              void* d_out, int out_size, void* d_ws, size_t ws_size,
                              hipStream_t stream) {
  const float* x  = (const float*)d_in[0];
  const float* w1 = (const float*)d_in[1];
  const float* b1 = (const float*)d_in[2];
  const float* w2 = (const float*)d_in[3];
  const float* b2 = (const float*)d_in[4];
  float* out = (float*)d_out;

  float* ws = (float*)d_ws;
  float* c0 = ws;                                      // 9,961,472 floats
  unsigned* hist    = (unsigned*)(ws + 9961472);       // 152*2048 = 311,296
  unsigned* kArr    = hist + 311296;
  unsigned* pvalArr = kArr + NPLANE;
  unsigned* gbArr   = pvalArr + NPLANE;
  unsigned* v1Arr   = gbArr + NPLANE;
  unsigned* v2Arr   = v1Arr + NPLANE;
  unsigned* flagArr = v2Arr + NPLANE;
  float* med  = (float*)(flagArr + NPLANE);
  float* sums = med + NPLANE;
  float* cnts = sums + NPLANE;
  float* h = out;   // conv1 scratch; fully overwritten by upsample

  init_kernel<<<1, 256, 0, stream>>>(kArr, pvalArr, gbArr, flagArr);
  hipMemsetAsync(hist, 0, (size_t)NPLANE * 2048 * sizeof(unsigned), stream);
  hipMemsetAsync(sums, 0, 2 * NPLANE * sizeof(float), stream);

  conv1_kernel<<<dim3(64, 32, 8), 256, 0, stream>>>(x, w1, b1, h);
  conv2_kernel<<<dim3(64, 19, 8), 256, 0, stream>>>(h, w2, b2, c0);
  upsample_kernel<<<dim3(256, NPLANE), 256, 0, stream>>>(c0, out);

  // radix select on f2key: bits 31:21, 20:10, 9:0 — recompute from c0 (L3-hot)
  hist_pass_kernel<<<dim3(8, NPLANE), 256, 0, stream>>>(c0, pvalArr, hist, 21, 0x7FFu, 0x00000000u);
  select_kernel<<<dim3(NPLANE), 256, 0, stream>>>(hist, kArr, pvalArr, gbArr,
      v1Arr, v2Arr, flagArr, 21, 0x7FFu, 2048, 0);
  hist_pass_kernel<<<dim3(8, NPLANE), 256, 0, stream>>>(c0, pvalArr, hist, 10, 0x7FFu, 0xFFE00000u);
  select_kernel<<<dim3(NPLANE), 256, 0, stream>>>(hist, kArr, pvalArr, gbArr,
      v1Arr, v2Arr, flagArr, 10, 0x7FFu, 2048, 0);
  hist_pass_kernel<<<dim3(8, NPLANE), 256, 0, stream>>>(c0, pvalArr, hist, 0, 0x3FFu, 0xFFFFFC00u);
  select_kernel<<<dim3(NPLANE), 256, 0, stream>>>(hist, kArr, pvalArr, gbArr,
      v1Arr, v2Arr, flagArr, 0, 0x3FFu, 1024, 1);
  minabove_kernel<<<dim3(16, NPLANE), 256, 0, stream>>>(out, flagArr, v1Arr, v2Arr);
  finalize_kernel<<<1, 256, 0, stream>>>(v1Arr, v2Arr, med);

  peak2_kernel<<<dim3(NPLANE, 4), 256, 0, stream>>>(out, med, sums, cnts);
  logits_kernel<<<1, 192, 0, stream>>>(sums, cnts, out + (out_size - NPLANE));
}